// Round 11
// baseline (191.954 us; speedup 1.0000x reference)
//
#include <hip/hip_runtime.h>

#define BB 16
#define HH 512
#define NH 32          // complex modes per h
#define LL 4096
#define TCH 64         // chunk length
#define NCH 64         // LL/TCH chunks per sequence
#define KA 128         // A-panel K: 64 u-taps + 64 state components

static_assert(TCH * NCH == LL, "chunking");

typedef __attribute__((ext_vector_type(8))) short bf16x8;
typedef __attribute__((ext_vector_type(4))) float f32x4;

// float->bf16 RNE via native convert (v_cvt_pk_bf16_f32 on gfx950)
static __device__ __forceinline__ unsigned short f2bf(float x) {
    return __builtin_bit_cast(unsigned short, (__bf16)x);
}
static __device__ __forceinline__ float bf2f(unsigned short b) {
    return __builtin_bit_cast(float, ((unsigned)b) << 16);
}
static __device__ __forceinline__ unsigned pack2(float a, float b) {
    return (unsigned)f2bf(a) | ((unsigned)f2bf(b) << 16);
}
// cheap tanh-form GELU: x * sigmoid(1.5957691*(x + 0.044715 x^3))
static __device__ __forceinline__ float gelu1(float x) {
    float a = fmaf(0.071354816f * x, x * x, 1.5957691f * x);
    return x * __builtin_amdgcn_rcpf(1.0f + __expf(-a));
}
static __device__ __forceinline__ unsigned gelu_pk(unsigned p) {
    float a = gelu1(bf2f((unsigned short)(p & 0xffffu)));
    float b = gelu1(bf2f((unsigned short)(p >> 16)));
    return pack2(a, b);
}

static __device__ __forceinline__ void gload_lds16(const void* g, void* l) {
#if __has_builtin(__builtin_amdgcn_global_load_lds)
    __builtin_amdgcn_global_load_lds(
        (const __attribute__((address_space(1))) unsigned int*)g,
        (__attribute__((address_space(3))) unsigned int*)l, 16, 0, 0);
#else
    *(uint4*)l = *(const uint4*)g;
#endif
}

// ---------------- k0: SSM scalar parameters ----------------
__global__ void k0_params(const float* __restrict__ C,
                          const float* __restrict__ log_dt,
                          const float* __restrict__ lAr,
                          const float* __restrict__ Aim,
                          float* __restrict__ c2R,  float* __restrict__ c2I,
                          float* __restrict__ ltR,  float* __restrict__ ltI,
                          float* __restrict__ xrA,  float* __restrict__ xiA)
{
    int tid = blockIdx.x * 256 + threadIdx.x;
    if (tid >= HH * NH) return;
    int h = tid >> 5;
    float dt = expf(log_dt[h]);
    float Ar = -expf(lAr[tid]);
    float Ai = Aim[tid];
    float xr = Ar * dt, xi = Ai * dt;      // log Lambda
    xrA[tid] = xr; xiA[tid] = xi;
    float er = expf(xr);
    float lr = er * cosf(xi);
    float li = er * sinf(xi);
    float wr = lr - 1.0f, wi = li;
    float inv = 1.0f / (Ar * Ar + Ai * Ai);
    float qr = (wr * Ar + wi * Ai) * inv;   // (Lam-1)/A
    float qi = (wi * Ar - wr * Ai) * inv;
    float cr = C[2 * tid], ci = C[2 * tid + 1];
    c2R[tid] =  2.0f * (cr * qr - ci * qi); // y = c2R*Re(s) + c2I*Im(s)
    c2I[tid] = -2.0f * (cr * qi + ci * qr);
    float eT = expf((float)TCH * xr);       // Lambda^TCH
    float aT = (float)TCH * xi;
    ltR[tid] = eT * cosf(aT);
    ltI[tid] = eT * sinf(aT);
}

// ---------------- kw: pack W (row-permuted for GLU) + bias ----------------
__global__ void kw_pack(const float* __restrict__ W, const float* __restrict__ bias,
                        unsigned short* __restrict__ Wp, float* __restrict__ bp)
{
    int tid = blockIdx.x * 256 + threadIdx.x;      // 65536
    int drow = tid >> 6;
    int kc = (tid & 63) * 8;
    int src = (drow & 1) ? (drow >> 1) + HH : (drow >> 1);
    const float4* s = (const float4*)(W + (size_t)src * HH + kc);
    float4 a = s[0], b4 = s[1];
    uint4 pack;
    pack.x = pack2(a.x, a.y);
    pack.y = pack2(a.z, a.w);
    pack.z = pack2(b4.x, b4.y);
    pack.w = pack2(b4.z, b4.w);
    *(uint4*)(Wp + (size_t)drow * HH + kc) = pack;
    if (tid < 2 * HH)
        bp[tid] = bias[(tid & 1) ? (tid >> 1) + HH : (tid >> 1)];
}

// ---------------- kA: build per-h matrices M|G (Apan) and V (Vpan) ----------------
// M diagonal absorbs D: M'[t][t] = k[0] + D_h  (exact algebra; D*u via MFMA)
__global__ __launch_bounds__(64) void kA_build(
    const float* __restrict__ c2R, const float* __restrict__ c2I,
    const float* __restrict__ xrA, const float* __restrict__ xiA,
    const float* __restrict__ Dv,
    unsigned short* __restrict__ Apan, unsigned short* __restrict__ Vpan)
{
    int h = blockIdx.x;
    int t = threadIdx.x;                  // 0..63
    __shared__ float s_xr[NH], s_xi[NH], s_cr[NH], s_ci[NH], s_k[TCH];
    if (t < NH) {
        s_xr[t] = xrA[h * NH + t]; s_xi[t] = xiA[h * NH + t];
        s_cr[t] = c2R[h * NH + t]; s_ci[t] = c2I[h * NH + t];
    }
    __syncthreads();
    {
        float d = (float)t;
        float acc = 0.f;
#pragma unroll
        for (int n = 0; n < NH; ++n) {
            float er = __expf(s_xr[n] * d);
            float sv, cv; __sincosf(s_xi[n] * d, &sv, &cv);
            acc = fmaf(s_cr[n], er * cv, fmaf(s_ci[n], er * sv, acc));
        }
        s_k[t] = acc;
    }
    __syncthreads();
    float k0d = s_k[0] + Dv[h];
    unsigned short row[KA];
#pragma unroll
    for (int tau = 0; tau < TCH; ++tau)
        row[tau] = f2bf((tau < t) ? s_k[t - tau] : (tau == t ? k0d : 0.f));
    float tp = (float)(t + 1);
#pragma unroll
    for (int n = 0; n < NH; ++n) {
        float er = __expf(s_xr[n] * tp);
        float sv, cv; __sincosf(s_xi[n] * tp, &sv, &cv);
        float pr = er * cv, pi = er * sv;           // Lam^{t+1}
        row[TCH + 2 * n]     = f2bf(fmaf(s_cr[n], pr,  s_ci[n] * pi));
        row[TCH + 2 * n + 1] = f2bf(fmaf(s_ci[n], pr, -s_cr[n] * pi));
    }
    {
        uint4* dst = (uint4*)(Apan + ((size_t)h * TCH + t) * KA);
        const uint4* src = (const uint4*)row;
#pragma unroll
        for (int i = 0; i < 16; ++i) dst[i] = src[i];
    }
    {
        int n = t >> 1, cm = t & 1;
        float xr = s_xr[n], xi = s_xi[n];
        unsigned short vrow[TCH];
#pragma unroll
        for (int tau = 0; tau < TCH; ++tau) {
            float p = (float)(TCH - 1 - tau);
            float er = __expf(xr * p);
            float sv, cv; __sincosf(xi * p, &sv, &cv);
            vrow[tau] = f2bf(cm ? er * sv : er * cv);
        }
        uint4* vd = (uint4*)(Vpan + ((size_t)h * TCH + t) * TCH);
        const uint4* vs = (const uint4*)vrow;
#pragma unroll
        for (int i = 0; i < 8; ++i) vd[i] = vs[i];
    }
}

// ---------------- kBCD: fused E-GEMM + inter-chunk scan + Y-GEMM ----------------
// Per wave: one (b,h). R11: register diet for occupancy — the kernel is
// latency-bound and was VGPR-capped at ~3 waves/EU (R10 peak ~130 VGPR from
// sfr-hoist + yp buffering). Revert to per-m S-fragment reads and direct
// uint2 stores (back-to-back stores to the same 128B lines merge in L2) ->
// peak ~90 VGPR -> 5 waves/EU (LDS-capped). waves_per_eu(2) kept: the one
// allocator setting that has never spilled (R5/R7/R9 all spilled when pinned).
__global__ __launch_bounds__(256)
__attribute__((amdgpu_waves_per_eu(2)))
void kBCD(
    const float* __restrict__ u,
    const unsigned short* __restrict__ Apan, const unsigned short* __restrict__ Vpan,
    const float* __restrict__ ltR, const float* __restrict__ ltI,
    unsigned short* __restrict__ yb)
{
    __shared__ unsigned short Sl[4][TCH * TCH];  // 4 waves x 8KB, XOR-swizzled
    int h = blockIdx.x & (HH - 1), g = blockIdx.x >> 9;
    int tid = threadIdx.x;
    int lane = tid & 63, w = tid >> 6;
    int b = g * 4 + w;
    int lrow = lane & 15, hi = lane >> 4, lk8 = hi * 8;
    const float* ug = u + ((size_t)b * HH + h) * LL;
    const unsigned short* Ap = Apan + (size_t)h * TCH * KA;
    const unsigned short* Vp = Vpan + (size_t)h * TCH * TCH;
    char* Sw = (char*)Sl[w];

    // ---- load u once, convert to bf16 B-fragments (shared by E- and Y-GEMM)
    bf16x8 ub[2][4];
#pragma unroll
    for (int ks = 0; ks < 2; ++ks)
#pragma unroll
        for (int n = 0; n < 4; ++n) {
            int c = n * 16 + lrow;
            const float* up = ug + c * TCH + ks * 32 + lk8;
            float4 f0 = *(const float4*)up, f1 = *(const float4*)(up + 4);
            bf16x8 v;
            v[0]=f2bf(f0.x); v[1]=f2bf(f0.y); v[2]=f2bf(f0.z); v[3]=f2bf(f0.w);
            v[4]=f2bf(f1.x); v[5]=f2bf(f1.y); v[6]=f2bf(f1.z); v[7]=f2bf(f1.w);
            ub[ks][n] = v;
        }

    // ---- E-GEMM (m-outer): E[j][c] = sum_tau V[j][tau] * u[c][tau]
#pragma unroll
    for (int m = 0; m < 4; ++m) {
        f32x4 accE[4];
#pragma unroll
        for (int n = 0; n < 4; ++n) { f32x4 z = {0.f,0.f,0.f,0.f}; accE[n] = z; }
#pragma unroll
        for (int ks = 0; ks < 2; ++ks) {
            bf16x8 vf = *(const bf16x8*)(Vp + (m * 16 + lrow) * TCH + ks * 32 + lk8);
#pragma unroll
            for (int n = 0; n < 4; ++n)
                accE[n] = __builtin_amdgcn_mfma_f32_16x16x32_bf16(vf, ub[ks][n], accE[n], 0, 0, 0);
        }
        int j0 = m * 16 + hi * 4;
#pragma unroll
        for (int n = 0; n < 4; ++n) {
            int c = n * 16 + lrow;
            uint2 p; p.x = pack2(accE[n][0], accE[n][1]); p.y = pack2(accE[n][2], accE[n][3]);
            *(uint2*)(Sw + c * 128 + ((2 * j0) ^ ((c & 7) << 4))) = p;
        }
    }
    asm volatile("s_waitcnt lgkmcnt(0)" ::: "memory");

    // ---- inter-chunk scan: lane n (<32) owns complex mode n; groups of 8
    if (lane < NH) {
        int n = lane;
        float ar = ltR[h * NH + n], ai = ltI[h * NH + n];
        float sr = 0.f, si = 0.f;
#pragma unroll
        for (int gg = 0; gg < 8; ++gg) {
            unsigned ev[8];
#pragma unroll
            for (int k = 0; k < 8; ++k)
                ev[k] = *(const unsigned*)(Sw + (gg * 8 + k) * 128 + ((4 * n) ^ (k << 4)));
#pragma unroll
            for (int k = 0; k < 8; ++k) {
                *(unsigned*)(Sw + (gg * 8 + k) * 128 + ((4 * n) ^ (k << 4))) = pack2(sr, si);
                float er = bf2f((unsigned short)(ev[k] & 0xffffu));
                float ei = bf2f((unsigned short)(ev[k] >> 16));
                float nsr = fmaf(ar, sr, fmaf(-ai, si, er));
                float nsi = fmaf(ar, si, fmaf(ai, sr, ei));
                sr = nsr; si = nsi;
            }
        }
    }
    asm volatile("s_waitcnt lgkmcnt(0)" ::: "memory");

    // ---- Y-GEMM (m-outer, direct store): Y = [M'|G] @ [u_c; S_c] -> yb (pre-GELU)
    unsigned short* yrow = yb + ((size_t)b * HH + h) * LL;
#pragma unroll
    for (int m = 0; m < 4; ++m) {
        f32x4 acc[4];
#pragma unroll
        for (int n = 0; n < 4; ++n) { f32x4 z = {0.f,0.f,0.f,0.f}; acc[n] = z; }
#pragma unroll
        for (int ks = 0; ks < 2; ++ks) {
            bf16x8 af = *(const bf16x8*)(Ap + (m * 16 + lrow) * KA + ks * 32 + lk8);
#pragma unroll
            for (int n = 0; n < 4; ++n)
                acc[n] = __builtin_amdgcn_mfma_f32_16x16x32_bf16(af, ub[ks][n], acc[n], 0, 0, 0);
        }
#pragma unroll
        for (int ks = 0; ks < 2; ++ks) {
            bf16x8 af = *(const bf16x8*)(Ap + (m * 16 + lrow) * KA + 64 + ks * 32 + lk8);
#pragma unroll
            for (int n = 0; n < 4; ++n) {
                int c = n * 16 + lrow;
                bf16x8 bfr = *(const bf16x8*)(Sw + c * 128 + ((ks * 64 + lk8 * 2) ^ ((c & 7) << 4)));
                acc[n] = __builtin_amdgcn_mfma_f32_16x16x32_bf16(af, bfr, acc[n], 0, 0, 0);
            }
        }
        int t0 = m * 16 + hi * 4;
#pragma unroll
        for (int n = 0; n < 4; ++n) {
            int c = n * 16 + lrow;
            uint2 pw;
            pw.x = pack2(acc[n][0], acc[n][1]);
            pw.y = pack2(acc[n][2], acc[n][3]);
            *(uint2*)(yrow + c * TCH + t0) = pw;
        }
    }
}

// ---------------- kT: transpose yb [b][h][l] -> yt [b*l][h], fused cheap GELU ----------------
__global__ __launch_bounds__(256) void kT_transpose(
    const unsigned short* __restrict__ yb, unsigned short* __restrict__ yt)
{
    __shared__ unsigned short T[64][130];        // stride 130 u16 -> 2-way max
    int bid = blockIdx.x;
    int lt = bid & 31;            // l-tile of 128
    int ht = (bid >> 5) & 7;      // h-tile of 64
    int b  = bid >> 8;
    int t = threadIdx.x;
#pragma unroll
    for (int r = 0; r < 4; ++r) {
        int chunk = r * 256 + t;                 // 1024 x 16B chunks
        int row = chunk >> 4;
        int c16 = chunk & 15;
        uint4 v = *(const uint4*)(yb + ((size_t)(b * HH + ht * 64 + row)) * LL
                                     + lt * 128 + c16 * 8);
        v.x = gelu_pk(v.x); v.y = gelu_pk(v.y);
        v.z = gelu_pk(v.z); v.w = gelu_pk(v.w);
        *(uint4*)&T[row][c16 * 8] = v;
    }
    __syncthreads();
    int oct = t & 7, lgrp = t >> 3;
    size_t obase = ((size_t)b * LL + (size_t)lt * 128) * HH + ht * 64 + oct * 8;
#pragma unroll
    for (int r = 0; r < 2; ++r) {
        int l = (r * 32 + lgrp) * 2;
        unsigned v[8];
#pragma unroll
        for (int k = 0; k < 8; ++k)
            v[k] = *(const unsigned*)&T[oct * 8 + k][l];
        uint4 w0, w1;
        w0.x = (v[0] & 0xffffu) | (v[1] << 16);
        w0.y = (v[2] & 0xffffu) | (v[3] << 16);
        w0.z = (v[4] & 0xffffu) | (v[5] << 16);
        w0.w = (v[6] & 0xffffu) | (v[7] << 16);
        w1.x = (v[0] >> 16) | (v[1] & 0xffff0000u);
        w1.y = (v[2] >> 16) | (v[3] & 0xffff0000u);
        w1.z = (v[4] >> 16) | (v[5] & 0xffff0000u);
        w1.w = (v[6] >> 16) | (v[7] & 0xffff0000u);
        *(uint4*)(yt + obase + (size_t)l * HH) = w0;
        *(uint4*)(yt + obase + (size_t)(l + 1) * HH) = w1;
    }
}

// ---------------- k4: GEMM z = Wp*y + bp, fused GLU (R10 version, measured good) ----------------
#define BM 128
#define BN 128
#define BKK 32

__global__ __launch_bounds__(256, 4) void k4_gemm(
    const unsigned short* __restrict__ Wp, const float* __restrict__ bp,
    const unsigned short* __restrict__ yt, float* __restrict__ out)
{
    __shared__ unsigned short As[BM * BKK];
    __shared__ unsigned short Bs[BN * BKK];
    int tid  = threadIdx.x;
    int bidx = (blockIdx.x & 7) * 512 + (blockIdx.x >> 3);  // XCD-contiguous
    int mtile = bidx & 7, ntile = bidx >> 3;
    int mbase = mtile * BM, nbase = ntile * BN;
    int lane = tid & 63;
    int wv = tid >> 6;
    int wr = wv >> 1, wc = wv & 1;
    int lrow = lane & 15;
    int hi = lane >> 4;

    f32x4 acc[4][4];
#pragma unroll
    for (int m = 0; m < 4; ++m)
#pragma unroll
        for (int n = 0; n < 4; ++n) { f32x4 z = {0.f,0.f,0.f,0.f}; acc[m][n] = z; }

    for (int kk = 0; kk < HH; kk += BKK) {
#pragma unroll
        for (int p = 0; p < 2; ++p) {
            int chunk = p * 256 + tid;
            int row = chunk >> 2;
            int c16 = chunk & 3;
            int kc  = (c16 ^ ((row >> 1) & 3)) * 8;   // pre-swizzled source
            gload_lds16(Wp + (size_t)(mbase + row) * HH + kk + kc, &As[chunk * 8]);
            gload_lds16(yt + (size_t)(nbase + row) * HH + kk + kc, &Bs[chunk * 8]);
        }
        __syncthreads();
        bf16x8 af[4], bfr[4];
#pragma unroll
        for (int m = 0; m < 4; ++m) {
            int row = wr * 64 + m * 16 + lrow;
            int slot = hi ^ ((row >> 1) & 3);         // swizzled read
            af[m] = *(const bf16x8*)&As[row * BKK + slot * 8];
        }
#pragma unroll
        for (int nf = 0; nf < 4; ++nf) {
            int row = wc * 64 + nf * 16 + lrow;
            int slot = hi ^ ((row >> 1) & 3);
            bfr[nf] = *(const bf16x8*)&Bs[row * BKK + slot * 8];
        }
#pragma unroll
        for (int m = 0; m < 4; ++m)
#pragma unroll
            for (int nf = 0; nf < 4; ++nf)
                acc[m][nf] = __builtin_amdgcn_mfma_f32_16x16x32_bf16(af[m], bfr[nf], acc[m][nf], 0, 0, 0);
        __syncthreads();
    }
#pragma unroll
    for (int m = 0; m < 4; ++m) {
        int go = mbase + wr * 64 + m * 16 + (hi * 4);
        float4 bv = *(const float4*)(bp + go);
#pragma unroll
        for (int nf = 0; nf < 4; ++nf) {
            int col  = nbase + wc * 64 + nf * 16 + lrow;
            int bcol = col >> 12;
            int lcol = col & (LL - 1);
            f32x4 v = acc[m][nf];
            float a0 = v[0] + bv.x, g0 = v[1] + bv.y;
            float a1 = v[2] + bv.z, g1 = v[3] + bv.w;
            float o0 = a0 / (1.0f + __expf(-g0));
            float o1 = a1 / (1.0f + __expf(-g1));
            size_t ob = ((size_t)bcol * HH + (size_t)(go >> 1)) * LL + lcol;
            out[ob] = o0;
            out[ob + LL] = o1;
        }
    }
}

extern "C" void kernel_launch(void* const* d_in, const int* in_sizes, int n_in,
                              void* d_out, int out_size, void* d_ws, size_t ws_size,
                              hipStream_t stream) {
    const float* u    = (const float*)d_in[0];
    const float* C    = (const float*)d_in[1];
    const float* ldt  = (const float*)d_in[2];
    const float* lar  = (const float*)d_in[3];
    const float* aim  = (const float*)d_in[4];
    const float* Dv   = (const float*)d_in[5];
    const float* W    = (const float*)d_in[6];
    const float* bias = (const float*)d_in[7];
    float* out = (float*)d_out;

    // ws layout (~79 MB)
    char* w = (char*)d_ws;
    float* c2R = (float*)w; w += (size_t)HH * NH * 4;
    float* c2I = (float*)w; w += (size_t)HH * NH * 4;
    float* ltR = (float*)w; w += (size_t)HH * NH * 4;
    float* ltI = (float*)w; w += (size_t)HH * NH * 4;
    float* xrA = (float*)w; w += (size_t)HH * NH * 4;
    float* xiA = (float*)w; w += (size_t)HH * NH * 4;
    float* bp  = (float*)w; w += (size_t)2 * HH * 4;
    unsigned short* Wp   = (unsigned short*)w; w += (size_t)2 * HH * HH * 2;
    unsigned short* Apan = (unsigned short*)w; w += (size_t)HH * TCH * KA * 2;   // 8MB
    unsigned short* Vpan = (unsigned short*)w; w += (size_t)HH * TCH * TCH * 2;  // 4MB
    unsigned short* yt   = (unsigned short*)w; w += (size_t)BB * LL * HH * 2;    // 64MB

    // yb (pre-transpose, pre-GELU, 64MB bf16) lives in d_out (134MB): dead
    // before k4; kT consumes it before k4 overwrites out.
    unsigned short* yb = (unsigned short*)d_out;

    k0_params   <<<dim3(64),   dim3(256), 0, stream>>>(C, ldt, lar, aim, c2R, c2I, ltR, ltI, xrA, xiA);
    kw_pack     <<<dim3(256),  dim3(256), 0, stream>>>(W, bias, Wp, bp);
    kA_build    <<<dim3(512),  dim3(64),  0, stream>>>(c2R, c2I, xrA, xiA, Dv, Apan, Vpan);
    kBCD        <<<dim3(2048), dim3(256), 0, stream>>>(u, Apan, Vpan, ltR, ltI, yb);
    kT_transpose<<<dim3(4096), dim3(256), 0, stream>>>(yb, yt);
    k4_gemm     <<<dim3(4096), dim3(256), 0, stream>>>(Wp, bp, yt, out);
}

// Round 12
// 185.322 us; speedup vs baseline: 1.0358x; 1.0358x over previous
//
#include <hip/hip_runtime.h>

#define BB 16
#define HH 512
#define NH 32          // complex modes per h
#define LL 4096
#define TCH 64         // chunk length
#define NCH 64         // LL/TCH chunks per sequence
#define KA 128         // A-panel K: 64 u-taps + 64 state components

static_assert(TCH * NCH == LL, "chunking");

typedef __attribute__((ext_vector_type(8))) short bf16x8;
typedef __attribute__((ext_vector_type(4))) float f32x4;

// float->bf16 RNE via native convert (v_cvt_pk_bf16_f32 on gfx950)
static __device__ __forceinline__ unsigned short f2bf(float x) {
    return __builtin_bit_cast(unsigned short, (__bf16)x);
}
static __device__ __forceinline__ float bf2f(unsigned short b) {
    return __builtin_bit_cast(float, ((unsigned)b) << 16);
}
static __device__ __forceinline__ unsigned pack2(float a, float b) {
    return (unsigned)f2bf(a) | ((unsigned)f2bf(b) << 16);
}
// cheap tanh-form GELU: x * sigmoid(1.5957691*(x + 0.044715 x^3))
static __device__ __forceinline__ float gelu1(float x) {
    float a = fmaf(0.071354816f * x, x * x, 1.5957691f * x);
    return x * __builtin_amdgcn_rcpf(1.0f + __expf(-a));
}
static __device__ __forceinline__ unsigned gelu_pk(unsigned p) {
    float a = gelu1(bf2f((unsigned short)(p & 0xffffu)));
    float b = gelu1(bf2f((unsigned short)(p >> 16)));
    return pack2(a, b);
}

static __device__ __forceinline__ void gload_lds16(const void* g, void* l) {
#if __has_builtin(__builtin_amdgcn_global_load_lds)
    __builtin_amdgcn_global_load_lds(
        (const __attribute__((address_space(1))) unsigned int*)g,
        (__attribute__((address_space(3))) unsigned int*)l, 16, 0, 0);
#else
    *(uint4*)l = *(const uint4*)g;
#endif
}

// ---------------- k0: SSM scalar parameters ----------------
__global__ void k0_params(const float* __restrict__ C,
                          const float* __restrict__ log_dt,
                          const float* __restrict__ lAr,
                          const float* __restrict__ Aim,
                          float* __restrict__ c2R,  float* __restrict__ c2I,
                          float* __restrict__ ltR,  float* __restrict__ ltI,
                          float* __restrict__ xrA,  float* __restrict__ xiA)
{
    int tid = blockIdx.x * 256 + threadIdx.x;
    if (tid >= HH * NH) return;
    int h = tid >> 5;
    float dt = expf(log_dt[h]);
    float Ar = -expf(lAr[tid]);
    float Ai = Aim[tid];
    float xr = Ar * dt, xi = Ai * dt;      // log Lambda
    xrA[tid] = xr; xiA[tid] = xi;
    float er = expf(xr);
    float lr = er * cosf(xi);
    float li = er * sinf(xi);
    float wr = lr - 1.0f, wi = li;
    float inv = 1.0f / (Ar * Ar + Ai * Ai);
    float qr = (wr * Ar + wi * Ai) * inv;   // (Lam-1)/A
    float qi = (wi * Ar - wr * Ai) * inv;
    float cr = C[2 * tid], ci = C[2 * tid + 1];
    c2R[tid] =  2.0f * (cr * qr - ci * qi); // y = c2R*Re(s) + c2I*Im(s)
    c2I[tid] = -2.0f * (cr * qi + ci * qr);
    float eT = expf((float)TCH * xr);       // Lambda^TCH
    float aT = (float)TCH * xi;
    ltR[tid] = eT * cosf(aT);
    ltI[tid] = eT * sinf(aT);
}

// ---------------- kw: pack W (row-permuted for GLU) + bias ----------------
__global__ void kw_pack(const float* __restrict__ W, const float* __restrict__ bias,
                        unsigned short* __restrict__ Wp, float* __restrict__ bp)
{
    int tid = blockIdx.x * 256 + threadIdx.x;      // 65536
    int drow = tid >> 6;
    int kc = (tid & 63) * 8;
    int src = (drow & 1) ? (drow >> 1) + HH : (drow >> 1);
    const float4* s = (const float4*)(W + (size_t)src * HH + kc);
    float4 a = s[0], b4 = s[1];
    uint4 pack;
    pack.x = pack2(a.x, a.y);
    pack.y = pack2(a.z, a.w);
    pack.z = pack2(b4.x, b4.y);
    pack.w = pack2(b4.z, b4.w);
    *(uint4*)(Wp + (size_t)drow * HH + kc) = pack;
    if (tid < 2 * HH)
        bp[tid] = bias[(tid & 1) ? (tid >> 1) + HH : (tid >> 1)];
}

// ---------------- kA: build per-h matrices M|G (Apan) and V (Vpan) ----------------
// M diagonal absorbs D: M'[t][t] = k[0] + D_h  (exact algebra; D*u via MFMA)
__global__ __launch_bounds__(64) void kA_build(
    const float* __restrict__ c2R, const float* __restrict__ c2I,
    const float* __restrict__ xrA, const float* __restrict__ xiA,
    const float* __restrict__ Dv,
    unsigned short* __restrict__ Apan, unsigned short* __restrict__ Vpan)
{
    int h = blockIdx.x;
    int t = threadIdx.x;                  // 0..63
    __shared__ float s_xr[NH], s_xi[NH], s_cr[NH], s_ci[NH], s_k[TCH];
    if (t < NH) {
        s_xr[t] = xrA[h * NH + t]; s_xi[t] = xiA[h * NH + t];
        s_cr[t] = c2R[h * NH + t]; s_ci[t] = c2I[h * NH + t];
    }
    __syncthreads();
    {
        float d = (float)t;
        float acc = 0.f;
#pragma unroll
        for (int n = 0; n < NH; ++n) {
            float er = __expf(s_xr[n] * d);
            float sv, cv; __sincosf(s_xi[n] * d, &sv, &cv);
            acc = fmaf(s_cr[n], er * cv, fmaf(s_ci[n], er * sv, acc));
        }
        s_k[t] = acc;
    }
    __syncthreads();
    float k0d = s_k[0] + Dv[h];
    unsigned short row[KA];
#pragma unroll
    for (int tau = 0; tau < TCH; ++tau)
        row[tau] = f2bf((tau < t) ? s_k[t - tau] : (tau == t ? k0d : 0.f));
    float tp = (float)(t + 1);
#pragma unroll
    for (int n = 0; n < NH; ++n) {
        float er = __expf(s_xr[n] * tp);
        float sv, cv; __sincosf(s_xi[n] * tp, &sv, &cv);
        float pr = er * cv, pi = er * sv;           // Lam^{t+1}
        row[TCH + 2 * n]     = f2bf(fmaf(s_cr[n], pr,  s_ci[n] * pi));
        row[TCH + 2 * n + 1] = f2bf(fmaf(s_ci[n], pr, -s_cr[n] * pi));
    }
    {
        uint4* dst = (uint4*)(Apan + ((size_t)h * TCH + t) * KA);
        const uint4* src = (const uint4*)row;
#pragma unroll
        for (int i = 0; i < 16; ++i) dst[i] = src[i];
    }
    {
        int n = t >> 1, cm = t & 1;
        float xr = s_xr[n], xi = s_xi[n];
        unsigned short vrow[TCH];
#pragma unroll
        for (int tau = 0; tau < TCH; ++tau) {
            float p = (float)(TCH - 1 - tau);
            float er = __expf(xr * p);
            float sv, cv; __sincosf(xi * p, &sv, &cv);
            vrow[tau] = f2bf(cm ? er * sv : er * cv);
        }
        uint4* vd = (uint4*)(Vpan + ((size_t)h * TCH + t) * TCH);
        const uint4* vs = (const uint4*)vrow;
#pragma unroll
        for (int i = 0; i < 8; ++i) vd[i] = vs[i];
    }
}

// ---------------- kBCD: fused E-GEMM + inter-chunk scan + Y-GEMM ----------------
// EXACT R10 body (measured ~58us, no spill-signature). R11's "register diet"
// let the allocator squeeze to 64 VGPR and spill (WRITE 93-104MB, 107us).
// The no-spill region here = high genuine pressure + loose bound.
__global__ __launch_bounds__(256)
__attribute__((amdgpu_waves_per_eu(2)))
void kBCD(
    const float* __restrict__ u,
    const unsigned short* __restrict__ Apan, const unsigned short* __restrict__ Vpan,
    const float* __restrict__ ltR, const float* __restrict__ ltI,
    unsigned short* __restrict__ yb)
{
    __shared__ unsigned short Sl[4][TCH * TCH];  // 4 waves x 8KB, XOR-swizzled
    int h = blockIdx.x & (HH - 1), g = blockIdx.x >> 9;
    int tid = threadIdx.x;
    int lane = tid & 63, w = tid >> 6;
    int b = g * 4 + w;
    int lrow = lane & 15, hi = lane >> 4, lk8 = hi * 8;
    const float* ug = u + ((size_t)b * HH + h) * LL;
    const unsigned short* Ap = Apan + (size_t)h * TCH * KA;
    const unsigned short* Vp = Vpan + (size_t)h * TCH * TCH;
    char* Sw = (char*)Sl[w];

    // ---- load u once, convert to bf16 B-fragments (shared by E- and Y-GEMM)
    bf16x8 ub[2][4];
#pragma unroll
    for (int ks = 0; ks < 2; ++ks)
#pragma unroll
        for (int n = 0; n < 4; ++n) {
            int c = n * 16 + lrow;
            const float* up = ug + c * TCH + ks * 32 + lk8;
            float4 f0 = *(const float4*)up, f1 = *(const float4*)(up + 4);
            bf16x8 v;
            v[0]=f2bf(f0.x); v[1]=f2bf(f0.y); v[2]=f2bf(f0.z); v[3]=f2bf(f0.w);
            v[4]=f2bf(f1.x); v[5]=f2bf(f1.y); v[6]=f2bf(f1.z); v[7]=f2bf(f1.w);
            ub[ks][n] = v;
        }

    // ---- E-GEMM (m-outer): E[j][c] = sum_tau V[j][tau] * u[c][tau]
#pragma unroll
    for (int m = 0; m < 4; ++m) {
        f32x4 accE[4];
#pragma unroll
        for (int n = 0; n < 4; ++n) { f32x4 z = {0.f,0.f,0.f,0.f}; accE[n] = z; }
#pragma unroll
        for (int ks = 0; ks < 2; ++ks) {
            bf16x8 vf = *(const bf16x8*)(Vp + (m * 16 + lrow) * TCH + ks * 32 + lk8);
#pragma unroll
            for (int n = 0; n < 4; ++n)
                accE[n] = __builtin_amdgcn_mfma_f32_16x16x32_bf16(vf, ub[ks][n], accE[n], 0, 0, 0);
        }
        int j0 = m * 16 + hi * 4;
#pragma unroll
        for (int n = 0; n < 4; ++n) {
            int c = n * 16 + lrow;
            uint2 p; p.x = pack2(accE[n][0], accE[n][1]); p.y = pack2(accE[n][2], accE[n][3]);
            *(uint2*)(Sw + c * 128 + ((2 * j0) ^ ((c & 7) << 4))) = p;
        }
    }
    asm volatile("s_waitcnt lgkmcnt(0)" ::: "memory");

    // ---- inter-chunk scan: lane n (<32) owns complex mode n; groups of 8
    if (lane < NH) {
        int n = lane;
        float ar = ltR[h * NH + n], ai = ltI[h * NH + n];
        float sr = 0.f, si = 0.f;
#pragma unroll
        for (int gg = 0; gg < 8; ++gg) {
            unsigned ev[8];
#pragma unroll
            for (int k = 0; k < 8; ++k)
                ev[k] = *(const unsigned*)(Sw + (gg * 8 + k) * 128 + ((4 * n) ^ (k << 4)));
#pragma unroll
            for (int k = 0; k < 8; ++k) {
                *(unsigned*)(Sw + (gg * 8 + k) * 128 + ((4 * n) ^ (k << 4))) = pack2(sr, si);
                float er = bf2f((unsigned short)(ev[k] & 0xffffu));
                float ei = bf2f((unsigned short)(ev[k] >> 16));
                float nsr = fmaf(ar, sr, fmaf(-ai, si, er));
                float nsi = fmaf(ar, si, fmaf(ai, sr, ei));
                sr = nsr; si = nsi;
            }
        }
    }
    asm volatile("s_waitcnt lgkmcnt(0)" ::: "memory");

    // ---- S-fragments: m-invariant, load once
    bf16x8 sfr[2][4];
#pragma unroll
    for (int ks = 0; ks < 2; ++ks)
#pragma unroll
        for (int n = 0; n < 4; ++n) {
            int c = n * 16 + lrow;
            sfr[ks][n] = *(const bf16x8*)(Sw + c * 128 + ((ks * 64 + lk8 * 2) ^ ((c & 7) << 4)));
        }

    // ---- Y-GEMM (m-outer): Y = [M'|G] @ [u_c; S_c], pack to yp regs
    uint2 yp[4][4];
#pragma unroll
    for (int m = 0; m < 4; ++m) {
        f32x4 acc[4];
#pragma unroll
        for (int n = 0; n < 4; ++n) { f32x4 z = {0.f,0.f,0.f,0.f}; acc[n] = z; }
#pragma unroll
        for (int ks = 0; ks < 2; ++ks) {
            bf16x8 af = *(const bf16x8*)(Ap + (m * 16 + lrow) * KA + ks * 32 + lk8);
#pragma unroll
            for (int n = 0; n < 4; ++n)
                acc[n] = __builtin_amdgcn_mfma_f32_16x16x32_bf16(af, ub[ks][n], acc[n], 0, 0, 0);
        }
#pragma unroll
        for (int ks = 0; ks < 2; ++ks) {
            bf16x8 af = *(const bf16x8*)(Ap + (m * 16 + lrow) * KA + 64 + ks * 32 + lk8);
#pragma unroll
            for (int n = 0; n < 4; ++n)
                acc[n] = __builtin_amdgcn_mfma_f32_16x16x32_bf16(af, sfr[ks][n], acc[n], 0, 0, 0);
        }
#pragma unroll
        for (int n = 0; n < 4; ++n) {
            yp[m][n].x = pack2(acc[n][0], acc[n][1]);
            yp[m][n].y = pack2(acc[n][2], acc[n][3]);
        }
    }
    asm volatile("s_waitcnt lgkmcnt(0)" ::: "memory");  // sfr reads done before Sw reuse

    // ---- scatter y into Sw (linear row layout, swizzled), then coalesced store
#pragma unroll
    for (int m = 0; m < 4; ++m) {
        int t0b = m * 32 + hi * 8;               // t0*2 bytes within row
#pragma unroll
        for (int n = 0; n < 4; ++n) {
            int c = n * 16 + lrow;
            *(uint2*)(Sw + c * 128 + (t0b ^ ((c & 7) << 4))) = yp[m][n];
        }
    }
    asm volatile("s_waitcnt lgkmcnt(0)" ::: "memory");
    unsigned short* yrow = yb + ((size_t)b * HH + h) * LL;
#pragma unroll
    for (int it = 0; it < 8; ++it) {
        int o = it * 1024 + lane * 16;           // byte offset in 8KB row
        int c = o >> 7;
        int sl = o & 127;
        uint4 v = *(const uint4*)(Sw + c * 128 + (sl ^ ((c & 7) << 4)));
        *(uint4*)((char*)yrow + o) = v;
    }
}

// ---------------- kT: transpose yb [b][h][l] -> yt [b*l][h], fused cheap GELU ----------------
__global__ __launch_bounds__(256) void kT_transpose(
    const unsigned short* __restrict__ yb, unsigned short* __restrict__ yt)
{
    __shared__ unsigned short T[64][130];        // stride 130 u16 -> 2-way max
    int bid = blockIdx.x;
    int lt = bid & 31;            // l-tile of 128
    int ht = (bid >> 5) & 7;      // h-tile of 64
    int b  = bid >> 8;
    int t = threadIdx.x;
#pragma unroll
    for (int r = 0; r < 4; ++r) {
        int chunk = r * 256 + t;                 // 1024 x 16B chunks
        int row = chunk >> 4;
        int c16 = chunk & 15;
        uint4 v = *(const uint4*)(yb + ((size_t)(b * HH + ht * 64 + row)) * LL
                                     + lt * 128 + c16 * 8);
        v.x = gelu_pk(v.x); v.y = gelu_pk(v.y);
        v.z = gelu_pk(v.z); v.w = gelu_pk(v.w);
        *(uint4*)&T[row][c16 * 8] = v;
    }
    __syncthreads();
    int oct = t & 7, lgrp = t >> 3;
    size_t obase = ((size_t)b * LL + (size_t)lt * 128) * HH + ht * 64 + oct * 8;
#pragma unroll
    for (int r = 0; r < 2; ++r) {
        int l = (r * 32 + lgrp) * 2;
        unsigned v[8];
#pragma unroll
        for (int k = 0; k < 8; ++k)
            v[k] = *(const unsigned*)&T[oct * 8 + k][l];
        uint4 w0, w1;
        w0.x = (v[0] & 0xffffu) | (v[1] << 16);
        w0.y = (v[2] & 0xffffu) | (v[3] << 16);
        w0.z = (v[4] & 0xffffu) | (v[5] << 16);
        w0.w = (v[6] & 0xffffu) | (v[7] << 16);
        w1.x = (v[0] >> 16) | (v[1] & 0xffff0000u);
        w1.y = (v[2] >> 16) | (v[3] & 0xffff0000u);
        w1.z = (v[4] >> 16) | (v[5] & 0xffff0000u);
        w1.w = (v[6] >> 16) | (v[7] & 0xffff0000u);
        *(uint4*)(yt + obase + (size_t)l * HH) = w0;
        *(uint4*)(yt + obase + (size_t)(l + 1) * HH) = w1;
    }
}

// ---------------- k4: GEMM z = Wp*y + bp, fused GLU ----------------
// R12: 2-phase double-buffered K-loop (T3 minimum recipe): issue next tile's
// global_load_lds BEFORE computing current tile, ONE barrier per K-step
// (halves barriers; load flight overlaps the 16-MFMA phase). Keeps R10's
// XCD-bijective swizzle + slot-XOR (conflicts 0, FETCH 46MB).
#define BM 128
#define BN 128
#define BKK 32
#define NKT (HH / BKK)   // 16 K-steps

__global__ __launch_bounds__(256, 4) void k4_gemm(
    const unsigned short* __restrict__ Wp, const float* __restrict__ bp,
    const unsigned short* __restrict__ yt, float* __restrict__ out)
{
    __shared__ unsigned short As[2][BM * BKK];
    __shared__ unsigned short Bs[2][BN * BKK];
    int tid  = threadIdx.x;
    int bidx = (blockIdx.x & 7) * 512 + (blockIdx.x >> 3);  // XCD-contiguous
    int mtile = bidx & 7, ntile = bidx >> 3;
    int mbase = mtile * BM, nbase = ntile * BN;
    int lane = tid & 63;
    int wv = tid >> 6;
    int wr = wv >> 1, wc = wv & 1;
    int lrow = lane & 15;
    int hi = lane >> 4;

    // staging addresses (per thread, fixed across K-steps except the kk offset)
    int srow0 = tid >> 2, sc16 = tid & 3;
    int skc0 = (sc16 ^ ((srow0 >> 1) & 3)) * 8;
    int srow1 = (256 + tid) >> 2;           // = 64 + (tid>>2)
    int skc1 = (sc16 ^ ((srow1 >> 1) & 3)) * 8;
    const unsigned short* aAddr0 = Wp + (size_t)(mbase + srow0) * HH + skc0;
    const unsigned short* bAddr0 = yt + (size_t)(nbase + srow0) * HH + skc0;
    const unsigned short* aAddr1 = Wp + (size_t)(mbase + srow1) * HH + skc1;
    const unsigned short* bAddr1 = yt + (size_t)(nbase + srow1) * HH + skc1;

    f32x4 acc[4][4];
#pragma unroll
    for (int m = 0; m < 4; ++m)
#pragma unroll
        for (int n = 0; n < 4; ++n) { f32x4 z = {0.f,0.f,0.f,0.f}; acc[m][n] = z; }

    // prologue: stage tile 0 into buffer 0
    gload_lds16(aAddr0, &As[0][tid * 8]);
    gload_lds16(bAddr0, &Bs[0][tid * 8]);
    gload_lds16(aAddr1, &As[0][(256 + tid) * 8]);
    gload_lds16(bAddr1, &Bs[0][(256 + tid) * 8]);
    __syncthreads();

    for (int t = 0; t < NKT; ++t) {
        int cur = t & 1;
        if (t + 1 < NKT) {
            int kk = (t + 1) * BKK;
            gload_lds16(aAddr0 + kk, &As[cur ^ 1][tid * 8]);
            gload_lds16(bAddr0 + kk, &Bs[cur ^ 1][tid * 8]);
            gload_lds16(aAddr1 + kk, &As[cur ^ 1][(256 + tid) * 8]);
            gload_lds16(bAddr1 + kk, &Bs[cur ^ 1][(256 + tid) * 8]);
        }
        bf16x8 af[4], bfr[4];
#pragma unroll
        for (int m = 0; m < 4; ++m) {
            int row = wr * 64 + m * 16 + lrow;
            int slot = hi ^ ((row >> 1) & 3);         // swizzled read
            af[m] = *(const bf16x8*)&As[cur][row * BKK + slot * 8];
        }
#pragma unroll
        for (int nf = 0; nf < 4; ++nf) {
            int row = wc * 64 + nf * 16 + lrow;
            int slot = hi ^ ((row >> 1) & 3);
            bfr[nf] = *(const bf16x8*)&Bs[cur][row * BKK + slot * 8];
        }
#pragma unroll
        for (int m = 0; m < 4; ++m)
#pragma unroll
            for (int nf = 0; nf < 4; ++nf)
                acc[m][nf] = __builtin_amdgcn_mfma_f32_16x16x32_bf16(af[m], bfr[nf], acc[m][nf], 0, 0, 0);
        __syncthreads();   // drains next-tile loads (vmcnt 0) + publishes buffer
    }
#pragma unroll
    for (int m = 0; m < 4; ++m) {
        int go = mbase + wr * 64 + m * 16 + (hi * 4);
        float4 bv = *(const float4*)(bp + go);
#pragma unroll
        for (int nf = 0; nf < 4; ++nf) {
            int col  = nbase + wc * 64 + nf * 16 + lrow;
            int bcol = col >> 12;
            int lcol = col & (LL - 1);
            f32x4 v = acc[m][nf];
            float a0 = v[0] + bv.x, g0 = v[1] + bv.y;
            float a1 = v[2] + bv.z, g1 = v[3] + bv.w;
            float o0 = a0 / (1.0f + __expf(-g0));
            float o1 = a1 / (1.0f + __expf(-g1));
            size_t ob = ((size_t)bcol * HH + (size_t)(go >> 1)) * LL + lcol;
            out[ob] = o0;
            out[ob + LL] = o1;
        }
    }
}

extern "C" void kernel_launch(void* const* d_in, const int* in_sizes, int n_in,
                              void* d_out, int out_size, void* d_ws, size_t ws_size,
                              hipStream_t stream) {
    const float* u    = (const float*)d_in[0];
    const float* C    = (const float*)d_in[1];
    const float* ldt  = (const float*)d_in[2];
    const float* lar  = (const float*)d_in[3];
    const float* aim  = (const float*)d_in[4];
    const float* Dv   = (const float*)d_in[5];
    const float* W    = (const float*)d_in[6];
    const float* bias = (const float*)d_in[7];
    float* out = (float*)d_out;

    // ws layout (~79 MB)
    char* w = (char*)d_ws;
    float* c2R = (float*)w; w += (size_t)HH * NH * 4;
    float* c2I = (float*)w; w += (size_t)HH * NH * 4;
    float* ltR = (float*)w; w += (size_t)HH * NH * 4;
    float* ltI = (float*)w; w += (size_t)HH * NH * 4;
    float* xrA = (float*)w; w += (size_t)HH * NH * 4;
    float* xiA = (float*)w; w += (size_t)HH * NH * 4;
    float* bp  = (float*)w; w += (size_t)2 * HH * 4;
    unsigned short* Wp   = (unsigned short*)w; w += (size_t)2 * HH * HH * 2;
    unsigned short* Apan = (unsigned short*)w; w += (size_t)HH * TCH * KA * 2;   // 8MB
    unsigned short* Vpan = (unsigned short*)w; w += (size_t)HH * TCH * TCH * 2;  // 4MB
    unsigned short* yt   = (unsigned short*)w; w += (size_t)BB * LL * HH * 2;    // 64MB

    // yb (pre-transpose, pre-GELU, 64MB bf16) lives in d_out (134MB): dead
    // before k4; kT consumes it before k4 overwrites out.
    unsigned short* yb = (unsigned short*)d_out;

    k0_params   <<<dim3(64),   dim3(256), 0, stream>>>(C, ldt, lar, aim, c2R, c2I, ltR, ltI, xrA, xiA);
    kw_pack     <<<dim3(256),  dim3(256), 0, stream>>>(W, bias, Wp, bp);
    kA_build    <<<dim3(512),  dim3(64),  0, stream>>>(c2R, c2I, xrA, xiA, Dv, Apan, Vpan);
    kBCD        <<<dim3(2048), dim3(256), 0, stream>>>(u, Apan, Vpan, ltR, ltI, yb);
    kT_transpose<<<dim3(4096), dim3(256), 0, stream>>>(yb, yt);
    k4_gemm     <<<dim3(4096), dim3(256), 0, stream>>>(Wp, bp, yt, out);
}

// Round 13
// 178.209 us; speedup vs baseline: 1.0771x; 1.0399x over previous
//
#include <hip/hip_runtime.h>

#define BB 16
#define HH 512
#define NH 32          // complex modes per h
#define LL 4096
#define TCH 64         // chunk length
#define NCH 64         // LL/TCH chunks per sequence
#define KA 128         // A-panel K: 64 u-taps + 64 state components

static_assert(TCH * NCH == LL, "chunking");

typedef __attribute__((ext_vector_type(8))) short bf16x8;
typedef __attribute__((ext_vector_type(4))) float f32x4;

// float->bf16 RNE via native convert (v_cvt_pk_bf16_f32 on gfx950)
static __device__ __forceinline__ unsigned short f2bf(float x) {
    return __builtin_bit_cast(unsigned short, (__bf16)x);
}
static __device__ __forceinline__ float bf2f(unsigned short b) {
    return __builtin_bit_cast(float, ((unsigned)b) << 16);
}
static __device__ __forceinline__ unsigned pack2(float a, float b) {
    return (unsigned)f2bf(a) | ((unsigned)f2bf(b) << 16);
}
// cheap tanh-form GELU: x * sigmoid(1.5957691*(x + 0.044715 x^3))
static __device__ __forceinline__ float gelu1(float x) {
    float a = fmaf(0.071354816f * x, x * x, 1.5957691f * x);
    return x * __builtin_amdgcn_rcpf(1.0f + __expf(-a));
}
static __device__ __forceinline__ unsigned gelu_pk(unsigned p) {
    float a = gelu1(bf2f((unsigned short)(p & 0xffffu)));
    float b = gelu1(bf2f((unsigned short)(p >> 16)));
    return pack2(a, b);
}

static __device__ __forceinline__ void gload_lds16(const void* g, void* l) {
#if __has_builtin(__builtin_amdgcn_global_load_lds)
    __builtin_amdgcn_global_load_lds(
        (const __attribute__((address_space(1))) unsigned int*)g,
        (__attribute__((address_space(3))) unsigned int*)l, 16, 0, 0);
#else
    *(uint4*)l = *(const uint4*)g;
#endif
}

// ---------------- k0: SSM scalar parameters ----------------
__global__ void k0_params(const float* __restrict__ C,
                          const float* __restrict__ log_dt,
                          const float* __restrict__ lAr,
                          const float* __restrict__ Aim,
                          float* __restrict__ c2R,  float* __restrict__ c2I,
                          float* __restrict__ ltR,  float* __restrict__ ltI,
                          float* __restrict__ xrA,  float* __restrict__ xiA)
{
    int tid = blockIdx.x * 256 + threadIdx.x;
    if (tid >= HH * NH) return;
    int h = tid >> 5;
    float dt = expf(log_dt[h]);
    float Ar = -expf(lAr[tid]);
    float Ai = Aim[tid];
    float xr = Ar * dt, xi = Ai * dt;      // log Lambda
    xrA[tid] = xr; xiA[tid] = xi;
    float er = expf(xr);
    float lr = er * cosf(xi);
    float li = er * sinf(xi);
    float wr = lr - 1.0f, wi = li;
    float inv = 1.0f / (Ar * Ar + Ai * Ai);
    float qr = (wr * Ar + wi * Ai) * inv;   // (Lam-1)/A
    float qi = (wi * Ar - wr * Ai) * inv;
    float cr = C[2 * tid], ci = C[2 * tid + 1];
    c2R[tid] =  2.0f * (cr * qr - ci * qi); // y = c2R*Re(s) + c2I*Im(s)
    c2I[tid] = -2.0f * (cr * qi + ci * qr);
    float eT = expf((float)TCH * xr);       // Lambda^TCH
    float aT = (float)TCH * xi;
    ltR[tid] = eT * cosf(aT);
    ltI[tid] = eT * sinf(aT);
}

// ---------------- kw: pack W (row-permuted for GLU) + bias ----------------
__global__ void kw_pack(const float* __restrict__ W, const float* __restrict__ bias,
                        unsigned short* __restrict__ Wp, float* __restrict__ bp)
{
    int tid = blockIdx.x * 256 + threadIdx.x;      // 65536
    int drow = tid >> 6;
    int kc = (tid & 63) * 8;
    int src = (drow & 1) ? (drow >> 1) + HH : (drow >> 1);
    const float4* s = (const float4*)(W + (size_t)src * HH + kc);
    float4 a = s[0], b4 = s[1];
    uint4 pack;
    pack.x = pack2(a.x, a.y);
    pack.y = pack2(a.z, a.w);
    pack.z = pack2(b4.x, b4.y);
    pack.w = pack2(b4.z, b4.w);
    *(uint4*)(Wp + (size_t)drow * HH + kc) = pack;
    if (tid < 2 * HH)
        bp[tid] = bias[(tid & 1) ? (tid >> 1) + HH : (tid >> 1)];
}

// ---------------- kA: build per-h matrices M|G (Apan) and V (Vpan) ----------------
// M diagonal absorbs D: M'[t][t] = k[0] + D_h  (exact algebra; D*u via MFMA)
__global__ __launch_bounds__(64) void kA_build(
    const float* __restrict__ c2R, const float* __restrict__ c2I,
    const float* __restrict__ xrA, const float* __restrict__ xiA,
    const float* __restrict__ Dv,
    unsigned short* __restrict__ Apan, unsigned short* __restrict__ Vpan)
{
    int h = blockIdx.x;
    int t = threadIdx.x;                  // 0..63
    __shared__ float s_xr[NH], s_xi[NH], s_cr[NH], s_ci[NH], s_k[TCH];
    if (t < NH) {
        s_xr[t] = xrA[h * NH + t]; s_xi[t] = xiA[h * NH + t];
        s_cr[t] = c2R[h * NH + t]; s_ci[t] = c2I[h * NH + t];
    }
    __syncthreads();
    {
        float d = (float)t;
        float acc = 0.f;
#pragma unroll
        for (int n = 0; n < NH; ++n) {
            float er = __expf(s_xr[n] * d);
            float sv, cv; __sincosf(s_xi[n] * d, &sv, &cv);
            acc = fmaf(s_cr[n], er * cv, fmaf(s_ci[n], er * sv, acc));
        }
        s_k[t] = acc;
    }
    __syncthreads();
    float k0d = s_k[0] + Dv[h];
    unsigned short row[KA];
#pragma unroll
    for (int tau = 0; tau < TCH; ++tau)
        row[tau] = f2bf((tau < t) ? s_k[t - tau] : (tau == t ? k0d : 0.f));
    float tp = (float)(t + 1);
#pragma unroll
    for (int n = 0; n < NH; ++n) {
        float er = __expf(s_xr[n] * tp);
        float sv, cv; __sincosf(s_xi[n] * tp, &sv, &cv);
        float pr = er * cv, pi = er * sv;           // Lam^{t+1}
        row[TCH + 2 * n]     = f2bf(fmaf(s_cr[n], pr,  s_ci[n] * pi));
        row[TCH + 2 * n + 1] = f2bf(fmaf(s_ci[n], pr, -s_cr[n] * pi));
    }
    {
        uint4* dst = (uint4*)(Apan + ((size_t)h * TCH + t) * KA);
        const uint4* src = (const uint4*)row;
#pragma unroll
        for (int i = 0; i < 16; ++i) dst[i] = src[i];
    }
    {
        int n = t >> 1, cm = t & 1;
        float xr = s_xr[n], xi = s_xi[n];
        unsigned short vrow[TCH];
#pragma unroll
        for (int tau = 0; tau < TCH; ++tau) {
            float p = (float)(TCH - 1 - tau);
            float er = __expf(xr * p);
            float sv, cv; __sincosf(xi * p, &sv, &cv);
            vrow[tau] = f2bf(cm ? er * sv : er * cv);
        }
        uint4* vd = (uint4*)(Vpan + ((size_t)h * TCH + t) * TCH);
        const uint4* vs = (const uint4*)vrow;
#pragma unroll
        for (int i = 0; i < 8; ++i) vd[i] = vs[i];
    }
}

// ---------------- kBCD: fused E-GEMM + inter-chunk scan + Y-GEMM ----------------
// EXACT R10 body (measured ~58us, no spill-signature).
__global__ __launch_bounds__(256)
__attribute__((amdgpu_waves_per_eu(2)))
void kBCD(
    const float* __restrict__ u,
    const unsigned short* __restrict__ Apan, const unsigned short* __restrict__ Vpan,
    const float* __restrict__ ltR, const float* __restrict__ ltI,
    unsigned short* __restrict__ yb)
{
    __shared__ unsigned short Sl[4][TCH * TCH];  // 4 waves x 8KB, XOR-swizzled
    int h = blockIdx.x & (HH - 1), g = blockIdx.x >> 9;
    int tid = threadIdx.x;
    int lane = tid & 63, w = tid >> 6;
    int b = g * 4 + w;
    int lrow = lane & 15, hi = lane >> 4, lk8 = hi * 8;
    const float* ug = u + ((size_t)b * HH + h) * LL;
    const unsigned short* Ap = Apan + (size_t)h * TCH * KA;
    const unsigned short* Vp = Vpan + (size_t)h * TCH * TCH;
    char* Sw = (char*)Sl[w];

    bf16x8 ub[2][4];
#pragma unroll
    for (int ks = 0; ks < 2; ++ks)
#pragma unroll
        for (int n = 0; n < 4; ++n) {
            int c = n * 16 + lrow;
            const float* up = ug + c * TCH + ks * 32 + lk8;
            float4 f0 = *(const float4*)up, f1 = *(const float4*)(up + 4);
            bf16x8 v;
            v[0]=f2bf(f0.x); v[1]=f2bf(f0.y); v[2]=f2bf(f0.z); v[3]=f2bf(f0.w);
            v[4]=f2bf(f1.x); v[5]=f2bf(f1.y); v[6]=f2bf(f1.z); v[7]=f2bf(f1.w);
            ub[ks][n] = v;
        }

#pragma unroll
    for (int m = 0; m < 4; ++m) {
        f32x4 accE[4];
#pragma unroll
        for (int n = 0; n < 4; ++n) { f32x4 z = {0.f,0.f,0.f,0.f}; accE[n] = z; }
#pragma unroll
        for (int ks = 0; ks < 2; ++ks) {
            bf16x8 vf = *(const bf16x8*)(Vp + (m * 16 + lrow) * TCH + ks * 32 + lk8);
#pragma unroll
            for (int n = 0; n < 4; ++n)
                accE[n] = __builtin_amdgcn_mfma_f32_16x16x32_bf16(vf, ub[ks][n], accE[n], 0, 0, 0);
        }
        int j0 = m * 16 + hi * 4;
#pragma unroll
        for (int n = 0; n < 4; ++n) {
            int c = n * 16 + lrow;
            uint2 p; p.x = pack2(accE[n][0], accE[n][1]); p.y = pack2(accE[n][2], accE[n][3]);
            *(uint2*)(Sw + c * 128 + ((2 * j0) ^ ((c & 7) << 4))) = p;
        }
    }
    asm volatile("s_waitcnt lgkmcnt(0)" ::: "memory");

    if (lane < NH) {
        int n = lane;
        float ar = ltR[h * NH + n], ai = ltI[h * NH + n];
        float sr = 0.f, si = 0.f;
#pragma unroll
        for (int gg = 0; gg < 8; ++gg) {
            unsigned ev[8];
#pragma unroll
            for (int k = 0; k < 8; ++k)
                ev[k] = *(const unsigned*)(Sw + (gg * 8 + k) * 128 + ((4 * n) ^ (k << 4)));
#pragma unroll
            for (int k = 0; k < 8; ++k) {
                *(unsigned*)(Sw + (gg * 8 + k) * 128 + ((4 * n) ^ (k << 4))) = pack2(sr, si);
                float er = bf2f((unsigned short)(ev[k] & 0xffffu));
                float ei = bf2f((unsigned short)(ev[k] >> 16));
                float nsr = fmaf(ar, sr, fmaf(-ai, si, er));
                float nsi = fmaf(ar, si, fmaf(ai, sr, ei));
                sr = nsr; si = nsi;
            }
        }
    }
    asm volatile("s_waitcnt lgkmcnt(0)" ::: "memory");

    bf16x8 sfr[2][4];
#pragma unroll
    for (int ks = 0; ks < 2; ++ks)
#pragma unroll
        for (int n = 0; n < 4; ++n) {
            int c = n * 16 + lrow;
            sfr[ks][n] = *(const bf16x8*)(Sw + c * 128 + ((ks * 64 + lk8 * 2) ^ ((c & 7) << 4)));
        }

    uint2 yp[4][4];
#pragma unroll
    for (int m = 0; m < 4; ++m) {
        f32x4 acc[4];
#pragma unroll
        for (int n = 0; n < 4; ++n) { f32x4 z = {0.f,0.f,0.f,0.f}; acc[n] = z; }
#pragma unroll
        for (int ks = 0; ks < 2; ++ks) {
            bf16x8 af = *(const bf16x8*)(Ap + (m * 16 + lrow) * KA + ks * 32 + lk8);
#pragma unroll
            for (int n = 0; n < 4; ++n)
                acc[n] = __builtin_amdgcn_mfma_f32_16x16x32_bf16(af, ub[ks][n], acc[n], 0, 0, 0);
        }
#pragma unroll
        for (int ks = 0; ks < 2; ++ks) {
            bf16x8 af = *(const bf16x8*)(Ap + (m * 16 + lrow) * KA + 64 + ks * 32 + lk8);
#pragma unroll
            for (int n = 0; n < 4; ++n)
                acc[n] = __builtin_amdgcn_mfma_f32_16x16x32_bf16(af, sfr[ks][n], acc[n], 0, 0, 0);
        }
#pragma unroll
        for (int n = 0; n < 4; ++n) {
            yp[m][n].x = pack2(acc[n][0], acc[n][1]);
            yp[m][n].y = pack2(acc[n][2], acc[n][3]);
        }
    }
    asm volatile("s_waitcnt lgkmcnt(0)" ::: "memory");

#pragma unroll
    for (int m = 0; m < 4; ++m) {
        int t0b = m * 32 + hi * 8;
#pragma unroll
        for (int n = 0; n < 4; ++n) {
            int c = n * 16 + lrow;
            *(uint2*)(Sw + c * 128 + (t0b ^ ((c & 7) << 4))) = yp[m][n];
        }
    }
    asm volatile("s_waitcnt lgkmcnt(0)" ::: "memory");
    unsigned short* yrow = yb + ((size_t)b * HH + h) * LL;
#pragma unroll
    for (int it = 0; it < 8; ++it) {
        int o = it * 1024 + lane * 16;
        int c = o >> 7;
        int sl = o & 127;
        uint4 v = *(const uint4*)(Sw + c * 128 + (sl ^ ((c & 7) << 4)));
        *(uint4*)((char*)yrow + o) = v;
    }
}

// ---------------- kT: transpose yb [b][h][l] -> yt [b*l][h], fused cheap GELU ----------------
__global__ __launch_bounds__(256) void kT_transpose(
    const unsigned short* __restrict__ yb, unsigned short* __restrict__ yt)
{
    __shared__ unsigned short T[64][130];
    int bid = blockIdx.x;
    int lt = bid & 31;
    int ht = (bid >> 5) & 7;
    int b  = bid >> 8;
    int t = threadIdx.x;
#pragma unroll
    for (int r = 0; r < 4; ++r) {
        int chunk = r * 256 + t;
        int row = chunk >> 4;
        int c16 = chunk & 15;
        uint4 v = *(const uint4*)(yb + ((size_t)(b * HH + ht * 64 + row)) * LL
                                     + lt * 128 + c16 * 8);
        v.x = gelu_pk(v.x); v.y = gelu_pk(v.y);
        v.z = gelu_pk(v.z); v.w = gelu_pk(v.w);
        *(uint4*)&T[row][c16 * 8] = v;
    }
    __syncthreads();
    int oct = t & 7, lgrp = t >> 3;
    size_t obase = ((size_t)b * LL + (size_t)lt * 128) * HH + ht * 64 + oct * 8;
#pragma unroll
    for (int r = 0; r < 2; ++r) {
        int l = (r * 32 + lgrp) * 2;
        unsigned v[8];
#pragma unroll
        for (int k = 0; k < 8; ++k)
            v[k] = *(const unsigned*)&T[oct * 8 + k][l];
        uint4 w0, w1;
        w0.x = (v[0] & 0xffffu) | (v[1] << 16);
        w0.y = (v[2] & 0xffffu) | (v[3] << 16);
        w0.z = (v[4] & 0xffffu) | (v[5] << 16);
        w0.w = (v[6] & 0xffffu) | (v[7] << 16);
        w1.x = (v[0] >> 16) | (v[1] & 0xffff0000u);
        w1.y = (v[2] >> 16) | (v[3] & 0xffff0000u);
        w1.z = (v[4] >> 16) | (v[5] & 0xffff0000u);
        w1.w = (v[6] >> 16) | (v[7] & 0xffff0000u);
        *(uint4*)(yt + obase + (size_t)l * HH) = w0;
        *(uint4*)(yt + obase + (size_t)(l + 1) * HH) = w1;
    }
}

// ---------------- k4: 256x256 GEMM, counted-vmcnt raw-barrier pipeline (T3+T4) ----------------
// 512 thr = 8 waves (2M x 4N), per-wave 128x64, BK=64, LDS 128KB (2-buf).
// Loads for K-tile kt+1 stay in flight across compute(kt): raw s_barrier +
// s_waitcnt vmcnt(8) (never 0 mid-loop). LDS rows XOR-swizzled ((r&7)<<4);
// gload source pre-swizzled to compensate (rule #21). K accumulation order
// unchanged (ascending, 32-granular) -> bit-identical output.
#define NKT4 8          // 512 / 64

__global__ __launch_bounds__(512, 2) void k4_gemm(
    const unsigned short* __restrict__ Wp, const float* __restrict__ bp,
    const unsigned short* __restrict__ yt, float* __restrict__ out)
{
    __shared__ unsigned short As4[2][256 * 64];   // 64KB
    __shared__ unsigned short Bs4[2][256 * 64];   // 64KB
    int tid = threadIdx.x;
    int bidx = (blockIdx.x & 7) * 128 + (blockIdx.x >> 3);  // XCD-contiguous, nwg=1024%8==0
    int mtile = bidx & 3, ntile = bidx >> 2;                 // mtile fastest: share B-panel in-XCD
    int mbase = mtile * 256, nbase = ntile * 256;
    int lane = tid & 63;
    int wv = tid >> 6;
    int wr = wv >> 2, wc = wv & 3;   // 2M x 4N waves
    int lrow = lane & 15;
    int hi = lane >> 4;
    int rx = (lrow & 7) << 4;        // read-side swizzle term (row&7 == lrow&7 here)

#define STAGE4(kt, buf) do {                                                   \
    _Pragma("unroll")                                                          \
    for (int rr = 0; rr < 4; ++rr) {                                           \
        int _r = rr * 64 + (tid >> 3);                                         \
        int _u = (tid & 7) ^ (_r & 7);                                         \
        gload_lds16(Wp + (size_t)(mbase + _r) * HH + (kt) * 64 + _u * 8,       \
                    &As4[buf][_r * 64 + (tid & 7) * 8]);                       \
        gload_lds16(yt + (size_t)(nbase + _r) * HH + (kt) * 64 + _u * 8,       \
                    &Bs4[buf][_r * 64 + (tid & 7) * 8]);                       \
    }                                                                          \
} while (0)

    f32x4 acc[8][4];
#pragma unroll
    for (int m = 0; m < 8; ++m)
#pragma unroll
        for (int n = 0; n < 4; ++n) { f32x4 z = {0.f,0.f,0.f,0.f}; acc[m][n] = z; }

    // prologue: 2-deep prefetch
    STAGE4(0, 0);
    STAGE4(1, 1);
    asm volatile("s_waitcnt vmcnt(8)" ::: "memory");   // tile 0 arrived
    asm volatile("s_barrier" ::: "memory");

#pragma unroll 1
    for (int kt = 0; kt < NKT4; ++kt) {
        int cur = kt & 1;
        const char* Ab = (const char*)&As4[cur][0];
        const char* Bb = (const char*)&Bs4[cur][0];
        // B-fragments for the whole K-tile (8 reads, reused by 4 quadrants)
        bf16x8 bfr[4][2];
#pragma unroll
        for (int n = 0; n < 4; ++n) {
            int R = wc * 64 + n * 16 + lrow;
#pragma unroll
            for (int ks = 0; ks < 2; ++ks)
                bfr[n][ks] = *(const bf16x8*)(Bb + R * 128 + ((ks * 64 + hi * 16) ^ rx));
        }
        // 4 quadrants of 2m x 4n x 2ks = 16 MFMA each
#pragma unroll
        for (int q = 0; q < 4; ++q) {
            bf16x8 af[2][2];
#pragma unroll
            for (int mi = 0; mi < 2; ++mi) {
                int R = wr * 128 + (q * 2 + mi) * 16 + lrow;
#pragma unroll
                for (int ks = 0; ks < 2; ++ks)
                    af[mi][ks] = *(const bf16x8*)(Ab + R * 128 + ((ks * 64 + hi * 16) ^ rx));
            }
#pragma unroll
            for (int mi = 0; mi < 2; ++mi)
#pragma unroll
                for (int n = 0; n < 4; ++n)
#pragma unroll
                    for (int ks = 0; ks < 2; ++ks)
                        acc[q * 2 + mi][n] = __builtin_amdgcn_mfma_f32_16x16x32_bf16(
                            af[mi][ks], bfr[n][ks], acc[q * 2 + mi][n], 0, 0, 0);
        }
        // sync tail: free buf[cur], refill it, ensure buf[cur^1] ready
        asm volatile("s_barrier" ::: "memory");            // all waves done reading buf[cur]
        if (kt + 2 < NKT4) {
            STAGE4(kt + 2, cur);
            asm volatile("s_waitcnt vmcnt(8)" ::: "memory");  // tile kt+1 complete (kt+2 in flight)
        } else {
            asm volatile("s_waitcnt vmcnt(0)" ::: "memory");  // drain remaining
        }
        asm volatile("s_barrier" ::: "memory");            // buf[cur^1] published
    }
#undef STAGE4

    // epilogue: bias + GLU (rows interleaved a,g)
#pragma unroll
    for (int m = 0; m < 8; ++m) {
        int go = mbase + wr * 128 + m * 16 + hi * 4;
        float4 bv = *(const float4*)(bp + go);
#pragma unroll
        for (int nf = 0; nf < 4; ++nf) {
            int col  = nbase + wc * 64 + nf * 16 + lrow;
            int bcol = col >> 12;
            int lcol = col & (LL - 1);
            f32x4 v = acc[m][nf];
            float a0 = v[0] + bv.x, g0 = v[1] + bv.y;
            float a1 = v[2] + bv.z, g1 = v[3] + bv.w;
            float o0 = a0 / (1.0f + __expf(-g0));
            float o1 = a1 / (1.0f + __expf(-g1));
            size_t ob = ((size_t)bcol * HH + (size_t)(go >> 1)) * LL + lcol;
            out[ob] = o0;
            out[ob + LL] = o1;
        }
    }
}

extern "C" void kernel_launch(void* const* d_in, const int* in_sizes, int n_in,
                              void* d_out, int out_size, void* d_ws, size_t ws_size,
                              hipStream_t stream) {
    const float* u    = (const float*)d_in[0];
    const float* C    = (const float*)d_in[1];
    const float* ldt  = (const float*)d_in[2];
    const float* lar  = (const float*)d_in[3];
    const float* aim  = (const float*)d_in[4];
    const float* Dv   = (const float*)d_in[5];
    const float* W    = (const float*)d_in[6];
    const float* bias = (const float*)d_in[7];
    float* out = (float*)d_out;

    // ws layout (~79 MB)
    char* w = (char*)d_ws;
    float* c2R = (float*)w; w += (size_t)HH * NH * 4;
    float* c2I = (float*)w; w += (size_t)HH * NH * 4;
    float* ltR = (float*)w; w += (size_t)HH * NH * 4;
    float* ltI = (float*)w; w += (size_t)HH * NH * 4;
    float* xrA = (float*)w; w += (size_t)HH * NH * 4;
    float* xiA = (float*)w; w += (size_t)HH * NH * 4;
    float* bp  = (float*)w; w += (size_t)2 * HH * 4;
    unsigned short* Wp   = (unsigned short*)w; w += (size_t)2 * HH * HH * 2;
    unsigned short* Apan = (unsigned short*)w; w += (size_t)HH * TCH * KA * 2;   // 8MB
    unsigned short* Vpan = (unsigned short*)w; w += (size_t)HH * TCH * TCH * 2;  // 4MB
    unsigned short* yt   = (unsigned short*)w; w += (size_t)BB * LL * HH * 2;    // 64MB

    // yb (pre-transpose, pre-GELU, 64MB bf16) lives in d_out (134MB): dead
    // before k4; kT consumes it before k4 overwrites out.
    unsigned short* yb = (unsigned short*)d_out;

    k0_params   <<<dim3(64),   dim3(256), 0, stream>>>(C, ldt, lar, aim, c2R, c2I, ltR, ltI, xrA, xiA);
    kw_pack     <<<dim3(256),  dim3(256), 0, stream>>>(W, bias, Wp, bp);
    kA_build    <<<dim3(512),  dim3(64),  0, stream>>>(c2R, c2I, xrA, xiA, Dv, Apan, Vpan);
    kBCD        <<<dim3(2048), dim3(256), 0, stream>>>(u, Apan, Vpan, ltR, ltI, yb);
    kT_transpose<<<dim3(4096), dim3(256), 0, stream>>>(yb, yt);
    k4_gemm     <<<dim3(1024), dim3(512), 0, stream>>>(Wp, bp, yt, out);
}